// Round 6
// baseline (137.746 us; speedup 1.0000x reference)
//
#include <hip/hip_runtime.h>
#include <hip/hip_bf16.h>
#include <math.h>

#define BATCH   4
#define NATOMS  2048
#define MNEIGH  100
#define NFEAT   42
#define H1      64
#define H2      32
#define NPAIR   (MNEIGH * NFEAT)        // 4200 (m,f) pairs per atom
#define NQUAD   (NPAIR * 3 / 4)         // 3150 float4 per atom

__device__ __forceinline__ float softplus_f(float z) {
    if (z > 20.f) return z;
    return log1pf(expf(z));
}

__device__ __forceinline__ float sigmoid_f(float z) {
    return 1.f / (1.f + expf(-z));
}

// ---------------------------------------------------------------------------
// Kernel 1: per-atom MLP + analytic dE/dx. 4 waves x 4 atoms-in-parallel.
// (unchanged from R5 — isolate the force variable)
// ---------------------------------------------------------------------------
__global__ __launch_bounds__(256) void mlp_kernel(
    const float* __restrict__ image,
    const float* __restrict__ W0, const float* __restrict__ b0,
    const float* __restrict__ W1, const float* __restrict__ b1,
    const float* __restrict__ W2, const float* __restrict__ b2,
    float* __restrict__ Ei_out,      // [B*N]
    float* __restrict__ dE)          // [B*N, F]
{
    __shared__ float sW0 [H1 * NFEAT];   // [h][f]  (dE pass)
    __shared__ float sW0T[NFEAT * H1];   // [f][h]  (z0 pass)
    __shared__ float sW1 [H2 * H1];      // [h2][h] (g1 pass)
    __shared__ float sW1T[H1 * H2];      // [h][h2] (z1 pass)
    __shared__ float sW2[H2];
    __shared__ float sb0[H1];
    __shared__ float sb1[H2];

    const int tid = threadIdx.x;
    for (int i = tid; i < H1 * NFEAT; i += 256) {
        const float v = W0[i];
        sW0[i] = v;
        const int h = i / NFEAT, f = i - h * NFEAT;
        sW0T[f * H1 + h] = v;
    }
    for (int i = tid; i < H2 * H1; i += 256) {
        const float v = W1[i];
        sW1[i] = v;
        const int h2 = i >> 6, h = i & 63;
        sW1T[h * H2 + h2] = v;
    }
    if (tid < H2) { sW2[tid] = W2[tid]; sb1[tid] = b1[tid]; }
    if (tid < H1) sb0[tid] = b0[tid];
    const float bias2 = b2[0];
    __syncthreads();    // the ONLY barrier

    const int wave = tid >> 6;
    const int lane = tid & 63;
    const int l2   = lane & 31;
    const int lf   = (lane < NFEAT) ? lane : NFEAT - 1;
    const int ga0  = blockIdx.x * 16 + wave * 4;   // 4 atoms per wave

    float img[4];
    #pragma unroll
    for (int a = 0; a < 4; ++a)
        img[a] = (lane < NFEAT) ? image[(size_t)(ga0 + a) * NFEAT + lane] : 0.f;

    float z0a[4], z0b[4];
    #pragma unroll
    for (int a = 0; a < 4; ++a) { z0a[a] = sb0[lane]; z0b[a] = 0.f; }
    #pragma unroll
    for (int f = 0; f < NFEAT; f += 2) {
        const float wA = sW0T[f * H1 + lane];
        const float wB = sW0T[(f + 1) * H1 + lane];
        #pragma unroll
        for (int a = 0; a < 4; ++a) {
            z0a[a] = fmaf(__shfl(img[a], f,     64), wA, z0a[a]);
            z0b[a] = fmaf(__shfl(img[a], f + 1, 64), wB, z0b[a]);
        }
    }
    float L0[4], d0[4];
    #pragma unroll
    for (int a = 0; a < 4; ++a) {
        const float z = z0a[a] + z0b[a];
        L0[a] = softplus_f(z);
        d0[a] = sigmoid_f(z);
    }

    float z1a[4], z1b[4];
    #pragma unroll
    for (int a = 0; a < 4; ++a) { z1a[a] = sb1[l2]; z1b[a] = 0.f; }
    #pragma unroll
    for (int h = 0; h < H1; h += 2) {
        const float wA = sW1T[h * H2 + l2];
        const float wB = sW1T[(h + 1) * H2 + l2];
        #pragma unroll
        for (int a = 0; a < 4; ++a) {
            z1a[a] = fmaf(__shfl(L0[a], h,     64), wA, z1a[a]);
            z1b[a] = fmaf(__shfl(L0[a], h + 1, 64), wB, z1b[a]);
        }
    }
    const float w2 = sW2[l2];
    float d1[4];
    #pragma unroll
    for (int a = 0; a < 4; ++a) {
        const float z = z1a[a] + z1b[a];
        const float L1 = softplus_f(z);
        d1[a] = sigmoid_f(z);
        float ei = (lane < H2) ? L1 * w2 : 0.f;
        #pragma unroll
        for (int off = 16; off > 0; off >>= 1) ei += __shfl_down(ei, off, 64);
        if (lane == 0) Ei_out[ga0 + a] = ei + bias2;
    }

    float g2v[4];
    #pragma unroll
    for (int a = 0; a < 4; ++a) g2v[a] = d1[a] * w2;
    float g1a[4], g1b[4];
    #pragma unroll
    for (int a = 0; a < 4; ++a) { g1a[a] = 0.f; g1b[a] = 0.f; }
    #pragma unroll
    for (int h2 = 0; h2 < H2; h2 += 2) {
        const float wA = sW1[h2 * H1 + lane];
        const float wB = sW1[(h2 + 1) * H1 + lane];
        #pragma unroll
        for (int a = 0; a < 4; ++a) {
            g1a[a] = fmaf(__shfl(g2v[a], h2,     64), wA, g1a[a]);
            g1b[a] = fmaf(__shfl(g2v[a], h2 + 1, 64), wB, g1b[a]);
        }
    }
    float g1[4];
    #pragma unroll
    for (int a = 0; a < 4; ++a) g1[a] = (g1a[a] + g1b[a]) * d0[a];

    float sa[4], sb[4];
    #pragma unroll
    for (int a = 0; a < 4; ++a) { sa[a] = 0.f; sb[a] = 0.f; }
    #pragma unroll
    for (int h = 0; h < H1; h += 2) {
        const float wA = sW0[h * NFEAT + lf];
        const float wB = sW0[(h + 1) * NFEAT + lf];
        #pragma unroll
        for (int a = 0; a < 4; ++a) {
            sa[a] = fmaf(__shfl(g1[a], h,     64), wA, sa[a]);
            sb[a] = fmaf(__shfl(g1[a], h + 1, 64), wB, sb[a]);
        }
    }
    if (lane < NFEAT) {
        #pragma unroll
        for (int a = 0; a < 4; ++a)
            dE[(size_t)(ga0 + a) * NFEAT + lane] = sa[a] + sb[a];
    }
}

// ---------------------------------------------------------------------------
// Kernel 2: Etot[b] = sum_n Ei[b,n]  (unchanged)
// ---------------------------------------------------------------------------
__global__ __launch_bounds__(256) void etot_kernel(
    const float* __restrict__ Ei, float* __restrict__ Etot)
{
    const int b = blockIdx.x;
    const int tid = threadIdx.x;
    float s = 0.f;
    for (int n = tid; n < NATOMS; n += 256) s += Ei[(size_t)b * NATOMS + n];
    #pragma unroll
    for (int off = 32; off > 0; off >>= 1) s += __shfl_down(s, off, 64);
    __shared__ float rb[4];
    if ((tid & 63) == 0) rb[tid >> 6] = s;
    __syncthreads();
    if (tid == 0) Etot[b] = rb[0] + rb[1] + rb[2] + rb[3];
}

// ---------------------------------------------------------------------------
// Kernel 3: force — ONE ATOM PER WAVE, zero in-loop barriers.
// Each wave streams its atom's 50.4 KB of dfeat as packed float4 (lane i ->
// flat index lane+64*i) and loads the 2 needed dE weights per float4
// DIRECTLY from global (dE is 1.4 MB, L2-resident; rides the same vmcnt
// pipeline as the stream). neighbor rows staged once in LDS (lgkmcnt,
// separate counter). Waves free-run -> loads stay in flight continuously;
// epilogue is a pure-shfl wave reduce. Rotation-select mapping = R4 form
// (numerically validated, absmax 0.0039).
// ---------------------------------------------------------------------------
__global__ __launch_bounds__(256) void force_kernel(
    const float* __restrict__ dfeat,
    const int*   __restrict__ neighbor,
    const float* __restrict__ dE,
    float* __restrict__ force)
{
    __shared__ int snbr[4 * MNEIGH];        // 4 waves -> 4 atoms per block

    const int tid  = threadIdx.x;
    const int wave = tid >> 6, lane = tid & 63;
    const int ga   = blockIdx.x * 4 + wave;     // this wave's atom
    const int b    = ga >> 11;                  // batch (4 | 2048: no straddle)

    // stage the block's 4 neighbor rows (coalesced), one barrier, then free-run
    for (int i = tid; i < 4 * MNEIGH; i += 256)
        snbr[i] = neighbor[(size_t)(blockIdx.x * 4) * MNEIGH + i];
    __syncthreads();

    const int* __restrict__ nb = snbr + wave * MNEIGH;
    const float* __restrict__ dErow = dE + (size_t)b * NATOMS * NFEAT;
    const float4* __restrict__ dfb4 =
        (const float4*)(dfeat + (size_t)ga * (NPAIR * 3));

    float a0 = 0.f, a1 = 0.f, a2 = 0.f;
    #pragma unroll 2
    for (int i = 0; i < 50; ++i) {
        const int q = lane + 64 * i;
        if (q < NQUAD) {                    // diverges only in the last iter
            const int i0 = 4 * q;
            const int p0 = i0 / 3;          // magic-mul
            const int r0 = i0 - 3 * p0;
            const int p1 = p0 + 1;          // max 4199, in bounds
            const int m0 = p0 / 42, f0 = p0 - 42 * m0;
            const int m1 = p1 / 42, f1 = p1 - 42 * m1;
            const int n0 = nb[m0], n1 = nb[m1];
            // unconditional loads (row 0 if padded), select after
            const float w0r = dErow[(size_t)((n0 > 0 ? n0 - 1 : 0)) * NFEAT + f0];
            const float w1r = dErow[(size_t)((n1 > 0 ? n1 - 1 : 0)) * NFEAT + f1];
            const float w0 = (n0 > 0) ? w0r : 0.f;
            const float w1 = (n1 > 0) ? w1r : 0.f;
            const float4 v = dfb4[q];
            const float s0 = fmaf(v.x, w0, v.w * w1);
            const float s1 = v.y * ((r0 >= 2) ? w1 : w0);
            const float s2 = v.z * ((r0 >= 1) ? w1 : w0);
            const bool e0 = (r0 == 0), e1 = (r0 == 1);
            a0 += e0 ? s0 : (e1 ? s2 : s1);
            a1 += e0 ? s1 : (e1 ? s0 : s2);
            a2 += e0 ? s2 : (e1 ? s1 : s0);
        }
    }

    // pure-shfl wave reduce, lane 0 stores
    #pragma unroll
    for (int off = 32; off > 0; off >>= 1) {
        a0 += __shfl_down(a0, off, 64);
        a1 += __shfl_down(a1, off, 64);
        a2 += __shfl_down(a2, off, 64);
    }
    if (lane == 0) {
        force[(size_t)ga * 3 + 0] = a0;
        force[(size_t)ga * 3 + 1] = a1;
        force[(size_t)ga * 3 + 2] = a2;
    }
}

// ---------------------------------------------------------------------------
extern "C" void kernel_launch(void* const* d_in, const int* in_sizes, int n_in,
                              void* d_out, int out_size, void* d_ws, size_t ws_size,
                              hipStream_t stream) {
    const float* image = (const float*)d_in[0];
    const float* dfeat = (const float*)d_in[1];
    // d_in[2] = Egroup_weight (unused by reference), d_in[3] = divider (unused)
    const float* W0 = (const float*)d_in[4];
    const float* b0 = (const float*)d_in[5];
    const float* W1 = (const float*)d_in[6];
    const float* b1 = (const float*)d_in[7];
    const float* W2 = (const float*)d_in[8];
    const float* b2 = (const float*)d_in[9];
    const int*   neighbor = (const int*)d_in[10];

    float* out   = (float*)d_out;
    float* Etot  = out;                          // [B,1]   -> 4
    float* Ei    = out + BATCH;                  // [B,N,1] -> 8192
    float* force = out + BATCH + BATCH * NATOMS; // [B,N,3] -> 24576
    float* dE    = (float*)d_ws;                 // [B,N,F] floats in workspace

    mlp_kernel<<<BATCH * NATOMS / 16, 256, 0, stream>>>(
        image, W0, b0, W1, b1, W2, b2, Ei, dE);
    etot_kernel<<<BATCH, 256, 0, stream>>>(Ei, Etot);
    force_kernel<<<BATCH * NATOMS / 4, 256, 0, stream>>>(dfeat, neighbor, dE, force);
}